// Round 1
// baseline (784.458 us; speedup 1.0000x reference)
//
#include <hip/hip_runtime.h>

// 3-layer LSTM (145->150->150->32), T=64, B=4096, fp16 MFMA compute, f32 state.
// Decomposition: each WG owns 16 batch rows for all 64 timesteps (batch rows are
// independent LSTMs). 8 waves/WG: wave = (gate i/f/g/o, N-half). Weights live in
// VGPRs as MFMA B-fragments. grid=256 (1 WG/CU).
// d_ws: inter-layer hidden sequence, f16, (T, B, 168) padded = 88,080,384 bytes.

typedef _Float16 f16;
typedef _Float16 f16x8 __attribute__((ext_vector_type(8)));
typedef float f32x4 __attribute__((ext_vector_type(4)));

#define T_STEPS 64
#define BATCH 4096

__device__ __forceinline__ float sigf(float x) { return 1.0f / (1.0f + __expf(-x)); }
__device__ __forceinline__ float tanh_f(float x) {
  float e = __expf(2.0f * x);          // +inf -> 1, 0 -> -1: both exact
  return 1.0f - 2.0f / (e + 1.0f);
}

// MODE 0: input f32 (T,B,IN_DIM) raw, output f16 ws (T,B,168)
// MODE 1: input f16 ws, output f16 ws (may alias: reads t+1 slab, writes t slab)
// MODE 2: input f16 ws, output f32 (T,B,32)
template <int IN_DIM, int H, int MODE>
__global__ __launch_bounds__(512, 2) void lstm_layer(
    const float* __restrict__ xin_f32, const f16* __restrict__ xin_f16,
    const float* __restrict__ w_ih, const float* __restrict__ w_hh,
    const float* __restrict__ b_ih, const float* __restrict__ b_hh,
    f16* __restrict__ hout, float* __restrict__ yout) {
  constexpr int KX = (IN_DIM + 31) / 32;   // K chunks, x side
  constexpr int XPAD = KX * 32;
  constexpr int XSTR = XPAD + 8;           // LDS row stride (f16): pad kills bank conflicts
  constexpr int KH = (H + 31) / 32;        // K chunks, h side
  constexpr int HSTR = KH * 32 + 8;
  constexpr int NPAD = ((H + 31) / 32) * 32;  // padded gate width (needs halves of 16)
  constexpr int NT = NPAD / 32;            // N tiles per wave (per half)
  constexpr int GROUPS = NPAD * 4;         // update groups: 4 rows x 1 col each
  constexpr int UPD_ITERS = (GROUPS + 511) / 512;
  constexpr int XIN_ELEMS = 16 * IN_DIM;   // per-tile input elems (MODE 0)
  constexpr int QX = (XIN_ELEMS + 511) / 512;
  constexpr int STG = (16 * XSTR) / 8;     // f16x8 copies per tile (MODE 1/2)
  static_assert(MODE == 0 || XSTR == 168, "ws stride must match LDS stride");
  static_assert(NPAD % 32 == 0, "");

  __shared__ __align__(16) f16 xbuf[2][16 * XSTR];
  __shared__ __align__(16) f16 hbuf[16 * HSTR];
  // gates[n][gate][rows]: stride 84 f32 per n => 8-bank spread, b128 aligned both sides
  __shared__ __align__(16) float gates[NPAD * 84];
  __shared__ __align__(16) float bias_lds[NPAD * 4];

  const int tid = threadIdx.x;
  const int l = tid & 63;
  const int wv = tid >> 6;     // 0..7
  const int gate = wv >> 1;    // 0..3 (i,f,g,o)
  const int half = wv & 1;     // N half
  const int lrow = l & 15;     // A row / B col / C col
  const int lk8 = (l >> 4) * 8;
  const int r0 = (l >> 4) * 4; // C row base
  const int b0 = blockIdx.x * 16;

  // ---------------- prologue ----------------
  {
    f16* xf = &xbuf[0][0];
    for (int i = tid; i < 2 * 16 * XSTR; i += 512) xf[i] = (f16)0.f;
    for (int i = tid; i < 16 * HSTR; i += 512) hbuf[i] = (f16)0.f;
    for (int i = tid; i < NPAD * 4; i += 512) {
      int n = i >> 2, g = i & 3;
      bias_lds[i] = (n < H) ? (b_ih[g * H + n] + b_hh[g * H + n]) : 0.f;
    }
  }

  // Weight B-fragments in registers (one-time, guarded scalar loads at edges;
  // out-of-range -> exact 0 so padded-A garbage can never produce NaN).
  const int rbase = half * (NPAD / 2) + lrow;
  f16x8 wx[KX][NT], wh[KH][NT];
#pragma unroll
  for (int kc = 0; kc < KX; ++kc)
#pragma unroll
    for (int nt = 0; nt < NT; ++nt) {
      f16x8 w;
#pragma unroll
      for (int j = 0; j < 8; ++j) {
        int k = kc * 32 + lk8 + j;
        int r = rbase + nt * 16;
        float v = (r < H && k < IN_DIM) ? w_ih[(size_t)(gate * H + r) * IN_DIM + k] : 0.f;
        w[j] = (f16)v;
      }
      wx[kc][nt] = w;
    }
#pragma unroll
  for (int kc = 0; kc < KH; ++kc)
#pragma unroll
    for (int nt = 0; nt < NT; ++nt) {
      f16x8 w;
#pragma unroll
      for (int j = 0; j < 8; ++j) {
        int k = kc * 32 + lk8 + j;
        int r = rbase + nt * 16;
        float v = (r < H && k < H) ? w_hh[(size_t)(gate * H + r) * H + k] : 0.f;
        w[j] = (f16)v;
      }
      wh[kc][nt] = w;
    }

  // stage x(0)
  if constexpr (MODE == 0) {
#pragma unroll
    for (int q = 0; q < QX; ++q) {
      int idx = q * 512 + tid;
      if (idx < XIN_ELEMS) {
        float v = xin_f32[(size_t)b0 * IN_DIM + idx];
        int r = idx / IN_DIM, c = idx - r * IN_DIM;
        xbuf[0][r * XSTR + c] = (f16)v;
      }
    }
  } else {
    if (tid < STG) {
      f16x8 v = *(const f16x8*)(xin_f16 + (size_t)b0 * 168 + tid * 8);
      *(f16x8*)(&xbuf[0][tid * 8]) = v;
    }
  }
  __syncthreads();

  float creg[UPD_ITERS][4];
#pragma unroll
  for (int it = 0; it < UPD_ITERS; ++it)
#pragma unroll
    for (int j = 0; j < 4; ++j) creg[it][j] = 0.f;

  float xv[QX];  // MODE 0 prefetch regs (dead otherwise)
  f16x8 pv;      // MODE 1/2 prefetch reg

  for (int t = 0; t < T_STEPS; ++t) {
    const int cur = t & 1, nxt = cur ^ 1;

    // -------- issue prefetch of x(t+1) (T14: loads early, LDS write late) --------
    if (t + 1 < T_STEPS) {
      if constexpr (MODE == 0) {
        const float* src = xin_f32 + ((size_t)(t + 1) * BATCH + b0) * IN_DIM;
#pragma unroll
        for (int q = 0; q < QX; ++q) {
          int idx = q * 512 + tid;
          xv[q] = (idx < XIN_ELEMS) ? src[idx] : 0.f;
        }
      } else {
        if (tid < STG)
          pv = *(const f16x8*)(xin_f16 + ((size_t)(t + 1) * BATCH + b0) * 168 + tid * 8);
      }
    }

    // -------- MFMA phase: gates = x@Wih^T + h@Whh^T --------
    f32x4 acc[NT];
#pragma unroll
    for (int nt = 0; nt < NT; ++nt) acc[nt] = f32x4{0.f, 0.f, 0.f, 0.f};
    {
      const f16* xb = &xbuf[cur][0];
#pragma unroll
      for (int kc = 0; kc < KX; ++kc) {
        f16x8 a = *(const f16x8*)(xb + lrow * XSTR + kc * 32 + lk8);
#pragma unroll
        for (int nt = 0; nt < NT; ++nt)
          acc[nt] = __builtin_amdgcn_mfma_f32_16x16x32_f16(a, wx[kc][nt], acc[nt], 0, 0, 0);
      }
#pragma unroll
      for (int kc = 0; kc < KH; ++kc) {
        f16x8 a = *(const f16x8*)(hbuf + lrow * HSTR + kc * 32 + lk8);
#pragma unroll
        for (int nt = 0; nt < NT; ++nt)
          acc[nt] = __builtin_amdgcn_mfma_f32_16x16x32_f16(a, wh[kc][nt], acc[nt], 0, 0, 0);
      }
    }
    // write raw gate preactivations (C layout: col=lane&15, rows r0..r0+3)
#pragma unroll
    for (int nt = 0; nt < NT; ++nt) {
      int n = half * (NPAD / 2) + nt * 16 + lrow;
      *(f32x4*)(&gates[n * 84 + gate * 20 + r0]) = acc[nt];
    }

    __syncthreads();  // bar B: gates visible; compiler drains vmcnt -> prefetch done

    // -------- write staged x(t+1) into the other buffer --------
    if (t + 1 < T_STEPS) {
      if constexpr (MODE == 0) {
#pragma unroll
        for (int q = 0; q < QX; ++q) {
          int idx = q * 512 + tid;
          if (idx < XIN_ELEMS) {
            int r = idx / IN_DIM, c = idx - r * IN_DIM;
            xbuf[nxt][r * XSTR + c] = (f16)xv[q];
          }
        }
      } else {
        if (tid < STG) *(f16x8*)(&xbuf[nxt][tid * 8]) = pv;
      }
    }

    // -------- elementwise update: c,h (c stays in registers) --------
#pragma unroll
    for (int it = 0; it < UPD_ITERS; ++it) {
      int grp = it * 512 + tid;
      if (grp < GROUPS) {
        int n = grp % NPAD;
        int rb = (grp / NPAD) * 4;
        if (n < H) {
          f32x4 gi = *(const f32x4*)(&gates[n * 84 + 0 + rb]);
          f32x4 gf = *(const f32x4*)(&gates[n * 84 + 20 + rb]);
          f32x4 gg = *(const f32x4*)(&gates[n * 84 + 40 + rb]);
          f32x4 go = *(const f32x4*)(&gates[n * 84 + 60 + rb]);
          f32x4 bs = *(const f32x4*)(&bias_lds[n * 4]);
#pragma unroll
          for (int j = 0; j < 4; ++j) {
            float iv = sigf(gi[j] + bs[0]);
            float fv = sigf(gf[j] + bs[1]);
            float gv = tanh_f(gg[j] + bs[2]);
            float ov = sigf(go[j] + bs[3]);
            float c = fv * creg[it][j] + iv * gv;
            creg[it][j] = c;
            float h = ov * tanh_f(c);
            hbuf[(rb + j) * HSTR + n] = (f16)h;
            if constexpr (MODE == 2) {
              yout[((size_t)t * BATCH + b0 + rb + j) * 32 + n] = h;
            } else {
              hout[((size_t)t * BATCH + b0 + rb + j) * 168 + n] = (f16)h;
            }
          }
        } else if constexpr (MODE != 2) {
          // zero the global pad columns so the next layer's staged tile is clean
#pragma unroll
          for (int j = 0; j < 4; ++j)
            hout[((size_t)t * BATCH + b0 + rb + j) * 168 + n] = (f16)0.f;
        }
      }
    }

    // bar C: LDS-only drain; leave global stores/loads in flight
    asm volatile("s_waitcnt lgkmcnt(0)\n\ts_barrier" ::: "memory");
  }
}

extern "C" void kernel_launch(void* const* d_in, const int* in_sizes, int n_in,
                              void* d_out, int out_size, void* d_ws, size_t ws_size,
                              hipStream_t stream) {
  const float* x = (const float*)d_in[0];
  const float* wih0 = (const float*)d_in[1];
  const float* whh0 = (const float*)d_in[2];
  const float* bih0 = (const float*)d_in[3];
  const float* bhh0 = (const float*)d_in[4];
  const float* wih1 = (const float*)d_in[5];
  const float* whh1 = (const float*)d_in[6];
  const float* bih1 = (const float*)d_in[7];
  const float* bhh1 = (const float*)d_in[8];
  const float* wih2 = (const float*)d_in[9];
  const float* whh2 = (const float*)d_in[10];
  const float* bih2 = (const float*)d_in[11];
  const float* bhh2 = (const float*)d_in[12];

  f16* hws = (f16*)d_ws;  // (T, B, 168) f16 = 88,080,384 B; layer1 runs in place
  float* out = (float*)d_out;

  dim3 grid(BATCH / 16), block(512);
  lstm_layer<145, 150, 0><<<grid, block, 0, stream>>>(x, nullptr, wih0, whh0, bih0, bhh0, hws, nullptr);
  lstm_layer<150, 150, 1><<<grid, block, 0, stream>>>(nullptr, hws, wih1, whh1, bih1, bhh1, hws, nullptr);
  lstm_layer<150, 32, 2><<<grid, block, 0, stream>>>(nullptr, hws, wih2, whh2, bih2, bhh2, nullptr, out);
}

// Round 2
// 653.912 us; speedup vs baseline: 1.1996x; 1.1996x over previous
//
#include <hip/hip_runtime.h>

// 3-layer LSTM (145->150->150->32), T=64, B=4096, fp16 MFMA compute, f32 state.
// Each WG owns 16 batch rows for all 64 timesteps. 8 waves/WG: wave = (gate, N-half).
// Weights live in VGPRs as MFMA B-fragments. grid=256 (1 WG/CU).
// R1: h stores to global are deferred one step and issued as coalesced f16x8 copies
//     from hbuf (whose row stride == ws stride 168); all barriers are lgkm-only so
//     global stores/loads never drain at a barrier.
// d_ws: inter-layer hidden sequence, f16, (T, B, 168) padded = 88,080,384 bytes.

typedef _Float16 f16;
typedef _Float16 f16x8 __attribute__((ext_vector_type(8)));
typedef float f32x4 __attribute__((ext_vector_type(4)));

#define T_STEPS 64
#define BATCH 4096

__device__ __forceinline__ float sigf(float x) { return 1.0f / (1.0f + __expf(-x)); }
__device__ __forceinline__ float tanh_f(float x) {
  float e = __expf(2.0f * x);          // +inf -> 1, 0 -> -1: both exact
  return 1.0f - 2.0f / (e + 1.0f);
}

// lgkm-only barrier: LDS visibility without draining global loads/stores.
#define BAR_LGKM() asm volatile("s_waitcnt lgkmcnt(0)\n\ts_barrier" ::: "memory")

// MODE 0: input f32 (T,B,IN_DIM) raw, output f16 ws (T,B,168)
// MODE 1: input f16 ws, output f16 ws (in-place: reads t+1 slab, writes t-1 slab, own rows)
// MODE 2: input f16 ws, output f32 (T,B,32)
template <int IN_DIM, int H, int MODE>
__global__ __launch_bounds__(512, 2) void lstm_layer(
    const float* __restrict__ xin_f32, const f16* __restrict__ xin_f16,
    const float* __restrict__ w_ih, const float* __restrict__ w_hh,
    const float* __restrict__ b_ih, const float* __restrict__ b_hh,
    f16* __restrict__ hout, float* __restrict__ yout) {
  constexpr int KX = (IN_DIM + 31) / 32;   // K chunks, x side
  constexpr int XPAD = KX * 32;
  constexpr int XSTR = XPAD + 8;           // LDS row stride (f16)
  constexpr int KH = (H + 31) / 32;        // K chunks, h side
  constexpr int HSTR = KH * 32 + 8;        // == 168 for H=150 (matches ws layout)
  constexpr int NPAD = ((H + 31) / 32) * 32;
  constexpr int NT = NPAD / 32;            // N tiles per wave (per half)
  constexpr int GROUPS = NPAD * 4;
  constexpr int UPD_ITERS = (GROUPS + 511) / 512;
  constexpr int XIN_ELEMS = 16 * IN_DIM;
  constexpr int QX = (XIN_ELEMS + 511) / 512;
  constexpr int STG = (16 * XSTR) / 8;     // f16x8 copies per input tile (MODE 1/2)
  constexpr int HCP = (16 * HSTR) / 8;     // f16x8 copies per h tile (MODE 0/1)
  static_assert(MODE == 0 || XSTR == 168, "ws stride must match LDS stride");
  static_assert(MODE == 2 || HSTR == 168, "h tile must match ws stride");

  __shared__ __align__(16) f16 xbuf[2][16 * XSTR];
  __shared__ __align__(16) f16 hbuf[16 * HSTR];
  // gates[n][gate][rows]: stride 84 f32 per n => 8-bank spread, b128 aligned both sides
  __shared__ __align__(16) float gates[NPAD * 84];
  __shared__ __align__(16) float bias_lds[NPAD * 4];

  const int tid = threadIdx.x;
  const int l = tid & 63;
  const int wv = tid >> 6;     // 0..7
  const int gate = wv >> 1;    // 0..3 (i,f,g,o)
  const int half = wv & 1;     // N half
  const int lrow = l & 15;     // A row / B col / C col
  const int lk8 = (l >> 4) * 8;
  const int r0 = (l >> 4) * 4; // C row base
  const int b0 = blockIdx.x * 16;

  // ---------------- prologue ----------------
  {
    f16* xf = &xbuf[0][0];
    for (int i = tid; i < 2 * 16 * XSTR; i += 512) xf[i] = (f16)0.f;
    for (int i = tid; i < 16 * HSTR; i += 512) hbuf[i] = (f16)0.f;
    for (int i = tid; i < NPAD * 4; i += 512) {
      int n = i >> 2, g = i & 3;
      bias_lds[i] = (n < H) ? (b_ih[g * H + n] + b_hh[g * H + n]) : 0.f;
    }
  }

  // Weight B-fragments in registers (one-time, guarded scalar loads at edges).
  const int rbase = half * (NPAD / 2) + lrow;
  f16x8 wx[KX][NT], wh[KH][NT];
#pragma unroll
  for (int kc = 0; kc < KX; ++kc)
#pragma unroll
    for (int nt = 0; nt < NT; ++nt) {
      f16x8 w;
#pragma unroll
      for (int j = 0; j < 8; ++j) {
        int k = kc * 32 + lk8 + j;
        int r = rbase + nt * 16;
        float v = (r < H && k < IN_DIM) ? w_ih[(size_t)(gate * H + r) * IN_DIM + k] : 0.f;
        w[j] = (f16)v;
      }
      wx[kc][nt] = w;
    }
#pragma unroll
  for (int kc = 0; kc < KH; ++kc)
#pragma unroll
    for (int nt = 0; nt < NT; ++nt) {
      f16x8 w;
#pragma unroll
      for (int j = 0; j < 8; ++j) {
        int k = kc * 32 + lk8 + j;
        int r = rbase + nt * 16;
        float v = (r < H && k < H) ? w_hh[(size_t)(gate * H + r) * H + k] : 0.f;
        w[j] = (f16)v;
      }
      wh[kc][nt] = w;
    }

  // stage x(0)
  if constexpr (MODE == 0) {
#pragma unroll
    for (int q = 0; q < QX; ++q) {
      int idx = q * 512 + tid;
      if (idx < XIN_ELEMS) {
        float v = xin_f32[(size_t)b0 * IN_DIM + idx];
        int r = idx / IN_DIM, c = idx - r * IN_DIM;
        xbuf[0][r * XSTR + c] = (f16)v;
      }
    }
  } else {
    if (tid < STG) {
      f16x8 v = *(const f16x8*)(xin_f16 + (size_t)b0 * 168 + tid * 8);
      *(f16x8*)(&xbuf[0][tid * 8]) = v;
    }
  }
  __syncthreads();

  float creg[UPD_ITERS][4];
#pragma unroll
  for (int it = 0; it < UPD_ITERS; ++it)
#pragma unroll
    for (int j = 0; j < 4; ++j) creg[it][j] = 0.f;

  float xv[QX];  // MODE 0 prefetch regs
  f16x8 pv;      // MODE 1/2 prefetch reg

  for (int t = 0; t < T_STEPS; ++t) {
    const int cur = t & 1, nxt = cur ^ 1;

    // -------- issue prefetch of x(t+1) --------
    if (t + 1 < T_STEPS) {
      if constexpr (MODE == 0) {
        const float* src = xin_f32 + ((size_t)(t + 1) * BATCH + b0) * IN_DIM;
#pragma unroll
        for (int q = 0; q < QX; ++q) {
          int idx = q * 512 + tid;
          xv[q] = (idx < XIN_ELEMS) ? src[idx] : 0.f;
        }
      } else {
        if (tid < STG)
          pv = *(const f16x8*)(xin_f16 + ((size_t)(t + 1) * BATCH + b0) * 168 + tid * 8);
      }
    }

    // -------- deferred coalesced h(t-1) store (hbuf row stride == ws stride) --------
    if constexpr (MODE != 2) {
      if (t > 0 && tid < HCP) {
        f16x8 v = *(const f16x8*)(&hbuf[tid * 8]);
        *(f16x8*)(hout + ((size_t)(t - 1) * BATCH + b0) * 168 + tid * 8) = v;
      }
    }

    // -------- MFMA phase: gates = x@Wih^T + h@Whh^T --------
    f32x4 acc[NT];
#pragma unroll
    for (int nt = 0; nt < NT; ++nt) acc[nt] = f32x4{0.f, 0.f, 0.f, 0.f};
    {
      const f16* xb = &xbuf[cur][0];
#pragma unroll
      for (int kc = 0; kc < KX; ++kc) {
        f16x8 a = *(const f16x8*)(xb + lrow * XSTR + kc * 32 + lk8);
#pragma unroll
        for (int nt = 0; nt < NT; ++nt)
          acc[nt] = __builtin_amdgcn_mfma_f32_16x16x32_f16(a, wx[kc][nt], acc[nt], 0, 0, 0);
      }
#pragma unroll
      for (int kc = 0; kc < KH; ++kc) {
        f16x8 a = *(const f16x8*)(hbuf + lrow * HSTR + kc * 32 + lk8);
#pragma unroll
        for (int nt = 0; nt < NT; ++nt)
          acc[nt] = __builtin_amdgcn_mfma_f32_16x16x32_f16(a, wh[kc][nt], acc[nt], 0, 0, 0);
      }
    }
    // write raw gate preactivations (C layout: col=lane&15, rows r0..r0+3)
#pragma unroll
    for (int nt = 0; nt < NT; ++nt) {
      int n = half * (NPAD / 2) + nt * 16 + lrow;
      *(f32x4*)(&gates[n * 84 + gate * 20 + r0]) = acc[nt];
    }

    BAR_LGKM();  // bar B: gates + h-copy reads complete; global ops stay in flight

    // -------- write staged x(t+1) into the other buffer --------
    if (t + 1 < T_STEPS) {
      if constexpr (MODE == 0) {
#pragma unroll
        for (int q = 0; q < QX; ++q) {
          int idx = q * 512 + tid;
          if (idx < XIN_ELEMS) {
            int r = idx / IN_DIM, c = idx - r * IN_DIM;
            xbuf[nxt][r * XSTR + c] = (f16)xv[q];
          }
        }
      } else {
        if (tid < STG) *(f16x8*)(&xbuf[nxt][tid * 8]) = pv;
      }
    }

    // -------- elementwise update: c,h (c stays in registers; h -> LDS only) --------
#pragma unroll
    for (int it = 0; it < UPD_ITERS; ++it) {
      int grp = it * 512 + tid;
      if (grp < GROUPS) {
        int n = grp % NPAD;
        int rb = (grp / NPAD) * 4;
        if (n < H) {
          f32x4 gi = *(const f32x4*)(&gates[n * 84 + 0 + rb]);
          f32x4 gf = *(const f32x4*)(&gates[n * 84 + 20 + rb]);
          f32x4 gg = *(const f32x4*)(&gates[n * 84 + 40 + rb]);
          f32x4 go = *(const f32x4*)(&gates[n * 84 + 60 + rb]);
          f32x4 bs = *(const f32x4*)(&bias_lds[n * 4]);
#pragma unroll
          for (int j = 0; j < 4; ++j) {
            float iv = sigf(gi[j] + bs[0]);
            float fv = sigf(gf[j] + bs[1]);
            float gv = tanh_f(gg[j] + bs[2]);
            float ov = sigf(go[j] + bs[3]);
            float c = fv * creg[it][j] + iv * gv;
            creg[it][j] = c;
            float h = ov * tanh_f(c);
            hbuf[(rb + j) * HSTR + n] = (f16)h;
            if constexpr (MODE == 2) {
              yout[((size_t)t * BATCH + b0 + rb + j) * 32 + n] = h;
            }
          }
        }
      }
    }

    BAR_LGKM();  // bar C: h(t) visible in LDS
  }

  // epilogue: store final h(T-1)
  if constexpr (MODE != 2) {
    if (tid < HCP) {
      f16x8 v = *(const f16x8*)(&hbuf[tid * 8]);
      *(f16x8*)(hout + ((size_t)(T_STEPS - 1) * BATCH + b0) * 168 + tid * 8) = v;
    }
  }
}

extern "C" void kernel_launch(void* const* d_in, const int* in_sizes, int n_in,
                              void* d_out, int out_size, void* d_ws, size_t ws_size,
                              hipStream_t stream) {
  const float* x = (const float*)d_in[0];
  const float* wih0 = (const float*)d_in[1];
  const float* whh0 = (const float*)d_in[2];
  const float* bih0 = (const float*)d_in[3];
  const float* bhh0 = (const float*)d_in[4];
  const float* wih1 = (const float*)d_in[5];
  const float* whh1 = (const float*)d_in[6];
  const float* bih1 = (const float*)d_in[7];
  const float* bhh1 = (const float*)d_in[8];
  const float* wih2 = (const float*)d_in[9];
  const float* whh2 = (const float*)d_in[10];
  const float* bih2 = (const float*)d_in[11];
  const float* bhh2 = (const float*)d_in[12];

  f16* hws = (f16*)d_ws;  // (T, B, 168) f16 = 88,080,384 B; layer1 runs in place
  float* out = (float*)d_out;

  dim3 grid(BATCH / 16), block(512);
  lstm_layer<145, 150, 0><<<grid, block, 0, stream>>>(x, nullptr, wih0, whh0, bih0, bhh0, hws, nullptr);
  lstm_layer<150, 150, 1><<<grid, block, 0, stream>>>(nullptr, hws, wih1, whh1, bih1, bhh1, hws, nullptr);
  lstm_layer<150, 32, 2><<<grid, block, 0, stream>>>(nullptr, hws, wih2, whh2, bih2, bhh2, nullptr, out);
}